// Round 5
// baseline (233.051 us; speedup 1.0000x reference)
//
#include <hip/hip_runtime.h>
#include <hip/hip_bf16.h>
#include <math.h>

// Problem constants
#define BB 16
#define QQ 100
#define NH 8
#define HD 32
#define HWN 4096
#define NORM_FACT 0.17677669529663687f   // 32^-0.5
#define QPAD 112        // q rows padded to 112 (7 tiles of 16)

typedef short bf16x8_t __attribute__((ext_vector_type(8)));
typedef float f32x4_t  __attribute__((ext_vector_type(4)));

__device__ __forceinline__ unsigned short bf16bits(float f) {
    __hip_bfloat16 h = __float2bfloat16(f);           // RNE
    return __builtin_bit_cast(unsigned short, h);
}
__device__ __forceinline__ float bf16tof(unsigned short u) {
    union { unsigned int i; float f; } x; x.i = (unsigned int)u << 16; return x.f;
}

// ---------------- K0: WqT (fp32 transpose) + Wk -> bf16 -----------------------
__global__ void k_prep(const float* __restrict__ Wq, const float* __restrict__ Wk,
                       float* __restrict__ WqT, unsigned short* __restrict__ Wkbf) {
    int idx = blockIdx.x;
    int h = threadIdx.x;
    if (idx < 256) {
        WqT[idx * 256 + h] = Wq[h * 256 + idx];
    } else {
        int r = idx - 256;
        Wkbf[r * 256 + h] = bf16bits(Wk[r * 256 + h]);
    }
}

// ---------------- K1: q-proj -> bf16 hi/lo split, padded to 112 rows ----------
__global__ __launch_bounds__(256) void k_qproj(const float* __restrict__ q,
                                               const float* __restrict__ WqT,
                                               const float* __restrict__ bq,
                                               unsigned short* __restrict__ qphi,
                                               unsigned short* __restrict__ qplo) {
    int blk = blockIdx.x;             // 16 b x 28 tiles of 4 rows
    int b = blk / 28, q0 = (blk % 28) * 4;
    int h = threadIdx.x;
    size_t obase = ((size_t)b * QPAD + q0) * 256 + h;
    if (q0 >= QQ) {                   // padding rows -> zeros
#pragma unroll
        for (int i = 0; i < 4; ++i) { qphi[obase + i * 256] = 0; qplo[obase + i * 256] = 0; }
        return;
    }
    __shared__ float qsh[4][256];
    int ibase = (b * QQ + q0) * 256;
#pragma unroll
    for (int i = 0; i < 4; ++i) qsh[i][h] = q[ibase + i * 256 + h];
    __syncthreads();
    float bias = bq[h];
    float a0 = bias, a1 = bias, a2 = bias, a3 = bias;
    for (int c = 0; c < 256; ++c) {
        float wv = WqT[c * 256 + h];
        a0 = fmaf(qsh[0][c], wv, a0);
        a1 = fmaf(qsh[1][c], wv, a1);
        a2 = fmaf(qsh[2][c], wv, a2);
        a3 = fmaf(qsh[3][c], wv, a3);
    }
    float a[4] = {a0 * NORM_FACT, a1 * NORM_FACT, a2 * NORM_FACT, a3 * NORM_FACT};
#pragma unroll
    for (int i = 0; i < 4; ++i) {
        unsigned short hi = bf16bits(a[i]);
        qphi[obase + i * 256] = hi;
        qplo[obase + i * 256] = bf16bits(a[i] - bf16tof(hi));
    }
}

// ---------------- K2a: kT[b][hw][c] bf16 <- k[b][c][hw] fp32 (LDS transpose) --
__global__ __launch_bounds__(256) void k_tconv(const float* __restrict__ k,
                                               unsigned short* __restrict__ kT) {
    int b = blockIdx.z, c0 = blockIdx.y * 64, hw0 = blockIdx.x * 64;
    int t = threadIdx.x;
    __shared__ float lds[64][65];
    const float* src = k + ((size_t)b * 256 + c0) * HWN + hw0;
    int col = t & 63, r0 = t >> 6;
#pragma unroll
    for (int i = 0; i < 16; ++i) {
        int r = i * 4 + r0;
        lds[r][col] = src[(size_t)r * HWN + col];
    }
    __syncthreads();
    int hw = t >> 2, cc = (t & 3) * 16;
    unsigned short* dst = kT + ((size_t)b * HWN + hw0 + hw) * 256 + c0 + cc;
    uint4 v0, v1;
    unsigned int* w0 = (unsigned int*)&v0;
    unsigned int* w1 = (unsigned int*)&v1;
#pragma unroll
    for (int j = 0; j < 4; ++j) {
        w0[j] = (unsigned int)bf16bits(lds[cc + 2*j + 0][hw])
              | ((unsigned int)bf16bits(lds[cc + 2*j + 1][hw]) << 16);
        w1[j] = (unsigned int)bf16bits(lds[cc + 8 + 2*j + 0][hw])
              | ((unsigned int)bf16bits(lds[cc + 8 + 2*j + 1][hw]) << 16);
    }
    *(uint4*)(dst)     = v0;
    *(uint4*)(dst + 8) = v1;
}

// ---------------- K2b+K3 fused: kpT = (Wk.k+bk)^T via MFMA, then score partials
// block = 4 waves; wave: phase A = 16 hw x 256 o; phase B = scores for its 16 hw
__global__ __launch_bounds__(256) void k_fused(const unsigned short* __restrict__ kT,
                                               const unsigned short* __restrict__ Wkbf,
                                               const float* __restrict__ bk,
                                               const unsigned short* __restrict__ qphi,
                                               const unsigned short* __restrict__ qplo,
                                               const int* __restrict__ mask,
                                               unsigned short* __restrict__ kpT,
                                               float* __restrict__ partial) {
    int b = blockIdx.y;
    int hwblk = blockIdx.x * 64;
    int t = threadIdx.x;
    int w = t >> 6, lane = t & 63;
    int n15 = lane & 15;      // hw col within wave tile / A-row within tile
    int kg = lane >> 4;       // k-group
    int hw = hwblk + w * 16 + n15;

    // ---- phase A: kproj MFMA (verified R4 pattern) ----
    f32x4_t acc[16];
#pragma unroll
    for (int m = 0; m < 16; ++m) acc[m] = f32x4_t{0.f, 0.f, 0.f, 0.f};

    const unsigned short* kTrow = kT + ((size_t)b * HWN + hw) * 256 + kg * 8;
    const unsigned short* wbase = Wkbf + (size_t)n15 * 256 + kg * 8;

#pragma unroll 2
    for (int ks = 0; ks < 8; ++ks) {
        bf16x8_t bfrag = *reinterpret_cast<const bf16x8_t*>(kTrow + ks * 32);
#pragma unroll
        for (int m = 0; m < 16; ++m) {
            bf16x8_t afrag = *reinterpret_cast<const bf16x8_t*>(wbase + (size_t)m * 16 * 256 + ks * 32);
            acc[m] = __builtin_amdgcn_mfma_f32_16x16x32_bf16(afrag, bfrag, acc[m], 0, 0, 0);
        }
    }

    // epilogue: bias + bf16 -> LDS tile [64 hw][256 o]
    __shared__ unsigned short tile2[64 * 264];     // pad 8 shorts
    int hw_l = w * 16 + n15;
#pragma unroll
    for (int m = 0; m < 16; ++m) {
        ushort4 pk;
        unsigned short* pkp = (unsigned short*)&pk;
#pragma unroll
        for (int r = 0; r < 4; ++r) {
            int o = m * 16 + kg * 4 + r;
            pkp[r] = bf16bits(acc[m][r] + bk[o]);
        }
        *(ushort4*)&tile2[hw_l * 264 + m * 16 + kg * 4] = pk;
    }
    __syncthreads();

    // coalesced global kpT write (for k_write's later use)
    int hw_r = t >> 2, sub = t & 3;
    unsigned short* dst = kpT + ((size_t)b * HWN + hwblk + hw_r) * 256;
#pragma unroll
    for (int j = 0; j < 8; ++j) {
        int o = j * 32 + sub * 8;
        uint4 v = *(uint4*)&tile2[hw_r * 264 + o];
        *(uint4*)(dst + o) = v;
    }

    // ---- phase B: score partial sums from the LDS tile ----
    float mm = mask[b * HWN + hw] ? 0.0f : 1.0f;
    const unsigned short* ahi_b = qphi + ((size_t)(b * QPAD + n15)) * 256 + kg * 8;
    const unsigned short* alo_b = qplo + ((size_t)(b * QPAD + n15)) * 256 + kg * 8;
    float sums[7][4] = {};
#pragma unroll 1
    for (int n = 0; n < NH; ++n) {
        bf16x8_t bfr = *reinterpret_cast<const bf16x8_t*>(&tile2[hw_l * 264 + n * 32 + kg * 8]);
#pragma unroll
        for (int mt = 0; mt < 7; ++mt) {
            bf16x8_t ahi = *reinterpret_cast<const bf16x8_t*>(ahi_b + (size_t)(mt * 16) * 256 + n * 32);
            bf16x8_t alo = *reinterpret_cast<const bf16x8_t*>(alo_b + (size_t)(mt * 16) * 256 + n * 32);
            f32x4_t a2 = {0.f, 0.f, 0.f, 0.f};
            a2 = __builtin_amdgcn_mfma_f32_16x16x32_bf16(ahi, bfr, a2, 0, 0, 0);
            a2 = __builtin_amdgcn_mfma_f32_16x16x32_bf16(alo, bfr, a2, 0, 0, 0);
#pragma unroll
            for (int r = 0; r < 4; ++r)
                sums[mt][r] += __expf(a2[r]) * mm;
        }
    }
#pragma unroll
    for (int mt = 0; mt < 7; ++mt)
#pragma unroll
        for (int r = 0; r < 4; ++r) {
            float v = sums[mt][r];
            v += __shfl_xor(v, 1, 64);
            v += __shfl_xor(v, 2, 64);
            v += __shfl_xor(v, 4, 64);
            v += __shfl_xor(v, 8, 64);
            if (n15 == 0) {
                int qrow = mt * 16 + kg * 4 + r;
                partial[((size_t)b * QPAD + qrow) * 256 + blockIdx.x * 4 + w] = v;
            }
        }
}

// ---------------- K4: inv_sum[b,q] — one block per (b,q), 256-slot reduce -----
__global__ __launch_bounds__(256) void k_invsum(const float* __restrict__ partial,
                                                float* __restrict__ inv) {
    int blk = blockIdx.x;            // 0..1599
    int b = blk / QQ, qq = blk % QQ;
    const float* p = partial + ((size_t)b * QPAD + qq) * 256;
    int t = threadIdx.x;
    float v = p[t];
#pragma unroll
    for (int off = 32; off; off >>= 1) v += __shfl_xor(v, off, 64);
    __shared__ float red[4];
    if ((t & 63) == 0) red[t >> 6] = v;
    __syncthreads();
    if (t == 0) inv[blk] = 1.0f / (red[0] + red[1] + red[2] + red[3]);
}

// ---------------- K5: write-pass via MFMA — normalized output -----------------
// grid (16 hw strips of 256, 7 q tiles of 16, 16 b); wave owns 64 hw
__global__ __launch_bounds__(256) void k_write(const unsigned short* __restrict__ qphi,
                                               const unsigned short* __restrict__ qplo,
                                               const unsigned short* __restrict__ kpT,
                                               const int* __restrict__ mask,
                                               const float* __restrict__ inv,
                                               float* __restrict__ out) {
    int hws = blockIdx.x, qt = blockIdx.y, b = blockIdx.z;
    int t = threadIdx.x, w = t >> 6, lane = t & 63;
    int n15 = lane & 15, kg = lane >> 4;
    int hw0 = hws * 256 + w * 64;
    float mm[4];
#pragma unroll
    for (int ht = 0; ht < 4; ++ht)
        mm[ht] = mask[b * HWN + hw0 + ht * 16 + n15] ? 0.0f : 1.0f;
    float invq[4];
#pragma unroll
    for (int r = 0; r < 4; ++r) {
        int qrow = qt * 16 + kg * 4 + r;
        invq[r] = (qrow < QQ) ? inv[b * QQ + qrow] : 0.0f;
    }
    const unsigned short* ahi_b = qphi + ((size_t)(b * QPAD + qt * 16 + n15)) * 256 + kg * 8;
    const unsigned short* alo_b = qplo + ((size_t)(b * QPAD + qt * 16 + n15)) * 256 + kg * 8;
    const unsigned short* brow  = kpT  + ((size_t)(b * HWN + hw0 + n15)) * 256 + kg * 8;
    __shared__ float lt[4][16][65];   // per-wave 16q x 64hw staging tile
#pragma unroll 1
    for (int n = 0; n < NH; ++n) {
        bf16x8_t bf[4];
#pragma unroll
        for (int ht = 0; ht < 4; ++ht)
            bf[ht] = *reinterpret_cast<const bf16x8_t*>(brow + (size_t)(ht * 16) * 256 + n * 32);
        bf16x8_t ahi = *reinterpret_cast<const bf16x8_t*>(ahi_b + n * 32);
        bf16x8_t alo = *reinterpret_cast<const bf16x8_t*>(alo_b + n * 32);
#pragma unroll
        for (int ht = 0; ht < 4; ++ht) {
            f32x4_t acc = {0.f, 0.f, 0.f, 0.f};
            acc = __builtin_amdgcn_mfma_f32_16x16x32_bf16(ahi, bf[ht], acc, 0, 0, 0);
            acc = __builtin_amdgcn_mfma_f32_16x16x32_bf16(alo, bf[ht], acc, 0, 0, 0);
#pragma unroll
            for (int r = 0; r < 4; ++r)
                lt[w][kg * 4 + r][ht * 16 + n15] = __expf(acc[r]) * mm[ht] * invq[r];
        }
        __syncthreads();
#pragma unroll
        for (int rr = 0; rr < 16; ++rr) {
            int qrow = qt * 16 + rr;
            if (qrow < QQ)
                out[(((size_t)(b * QQ + qrow)) * NH + n) * HWN + hw0 + lane] = lt[w][rr][lane];
        }
        __syncthreads();
    }
}

extern "C" void kernel_launch(void* const* d_in, const int* in_sizes, int n_in,
                              void* d_out, int out_size, void* d_ws, size_t ws_size,
                              hipStream_t stream) {
    const float* q    = (const float*)d_in[0];
    const float* k    = (const float*)d_in[1];
    const float* Wq   = (const float*)d_in[2];
    const float* bq   = (const float*)d_in[3];
    const float* Wk   = (const float*)d_in[4];
    const float* bk   = (const float*)d_in[5];
    const int*   mask = (const int*)d_in[6];
    float* out = (float*)d_out;

    char* base = (char*)d_ws;
    unsigned short* kT   = (unsigned short*)(base);              // 33,554,432 B
    unsigned short* kpT  = (unsigned short*)(base + 33554432);   // 33,554,432 B
    unsigned short* qphi = (unsigned short*)(base + 67108864);   //    917,504 B
    unsigned short* qplo = (unsigned short*)(base + 68026368);   //    917,504 B
    float*  WqT     = (float*)(base + 68943872);                 //    262,144 B
    unsigned short* Wkbf = (unsigned short*)(base + 69206016);   //    131,072 B
    float*  partial = (float*)(base + 69337088);                 //  1,835,008 B
    float*  inv     = (float*)(base + 71172096);                 //      6,400 B
    if (ws_size < (size_t)71178496) return;

    k_prep  <<<dim3(512), dim3(256), 0, stream>>>(Wq, Wk, WqT, Wkbf);
    k_qproj <<<dim3(448), dim3(256), 0, stream>>>(q, WqT, bq, qphi, qplo);
    k_tconv <<<dim3(64, 4, 16), dim3(256), 0, stream>>>(k, kT);
    k_fused <<<dim3(64, 16), dim3(256), 0, stream>>>(kT, Wkbf, bk, qphi, qplo, mask, kpT, partial);
    k_invsum<<<dim3(1600), dim3(256), 0, stream>>>(partial, inv);
    k_write <<<dim3(16, 7, 16), dim3(256), 0, stream>>>(qphi, qplo, kpT, mask, inv, out);
}

// Round 7
// 222.967 us; speedup vs baseline: 1.0452x; 1.0452x over previous
//
#include <hip/hip_runtime.h>
#include <hip/hip_bf16.h>
#include <math.h>

// Problem constants
#define BB 16
#define QQ 100
#define NH 8
#define HD 32
#define HWN 4096
#define NORM_FACT 0.17677669529663687f   // 32^-0.5
#define QPAD 112        // q rows padded to 112 (7 tiles of 16)

typedef short bf16x8_t __attribute__((ext_vector_type(8)));
typedef float f32x4_t  __attribute__((ext_vector_type(4)));

__device__ __forceinline__ unsigned short bf16bits(float f) {
    __hip_bfloat16 h = __float2bfloat16(f);           // RNE
    return __builtin_bit_cast(unsigned short, h);
}
__device__ __forceinline__ float bf16tof(unsigned short u) {
    union { unsigned int i; float f; } x; x.i = (unsigned int)u << 16; return x.f;
}

// ---------------- K0: WqT (fp32 transpose) + Wk -> bf16 -----------------------
__global__ void k_prep(const float* __restrict__ Wq, const float* __restrict__ Wk,
                       float* __restrict__ WqT, unsigned short* __restrict__ Wkbf) {
    int idx = blockIdx.x;
    int h = threadIdx.x;
    if (idx < 256) {
        WqT[idx * 256 + h] = Wq[h * 256 + idx];
    } else {
        int r = idx - 256;
        Wkbf[r * 256 + h] = bf16bits(Wk[r * 256 + h]);
    }
}

// ---------------- K1: q-proj -> bf16 hi/lo split, padded to 112 rows ----------
__global__ __launch_bounds__(256) void k_qproj(const float* __restrict__ q,
                                               const float* __restrict__ WqT,
                                               const float* __restrict__ bq,
                                               unsigned short* __restrict__ qphi,
                                               unsigned short* __restrict__ qplo) {
    int blk = blockIdx.x;             // 16 b x 28 tiles of 4 rows
    int b = blk / 28, q0 = (blk % 28) * 4;
    int h = threadIdx.x;
    size_t obase = ((size_t)b * QPAD + q0) * 256 + h;
    if (q0 >= QQ) {                   // padding rows -> zeros
#pragma unroll
        for (int i = 0; i < 4; ++i) { qphi[obase + i * 256] = 0; qplo[obase + i * 256] = 0; }
        return;
    }
    __shared__ float qsh[4][256];
    int ibase = (b * QQ + q0) * 256;
#pragma unroll
    for (int i = 0; i < 4; ++i) qsh[i][h] = q[ibase + i * 256 + h];
    __syncthreads();
    float bias = bq[h];
    float a0 = bias, a1 = bias, a2 = bias, a3 = bias;
    for (int c = 0; c < 256; ++c) {
        float wv = WqT[c * 256 + h];
        a0 = fmaf(qsh[0][c], wv, a0);
        a1 = fmaf(qsh[1][c], wv, a1);
        a2 = fmaf(qsh[2][c], wv, a2);
        a3 = fmaf(qsh[3][c], wv, a3);
    }
    float a[4] = {a0 * NORM_FACT, a1 * NORM_FACT, a2 * NORM_FACT, a3 * NORM_FACT};
#pragma unroll
    for (int i = 0; i < 4; ++i) {
        unsigned short hi = bf16bits(a[i]);
        qphi[obase + i * 256] = hi;
        qplo[obase + i * 256] = bf16bits(a[i] - bf16tof(hi));
    }
}

// ---------------- K2a: kT[b][hw][c] bf16 <- k[b][c][hw] fp32 (LDS transpose) --
__global__ __launch_bounds__(256) void k_tconv(const float* __restrict__ k,
                                               unsigned short* __restrict__ kT) {
    int b = blockIdx.z, c0 = blockIdx.y * 64, hw0 = blockIdx.x * 64;
    int t = threadIdx.x;
    __shared__ float lds[64][65];
    const float* src = k + ((size_t)b * 256 + c0) * HWN + hw0;
    int col = t & 63, r0 = t >> 6;
#pragma unroll
    for (int i = 0; i < 16; ++i) {
        int r = i * 4 + r0;
        lds[r][col] = src[(size_t)r * HWN + col];
    }
    __syncthreads();
    int hw = t >> 2, cc = (t & 3) * 16;
    unsigned short* dst = kT + ((size_t)b * HWN + hw0 + hw) * 256 + c0 + cc;
    uint4 v0, v1;
    unsigned int* w0 = (unsigned int*)&v0;
    unsigned int* w1 = (unsigned int*)&v1;
#pragma unroll
    for (int j = 0; j < 4; ++j) {
        w0[j] = (unsigned int)bf16bits(lds[cc + 2*j + 0][hw])
              | ((unsigned int)bf16bits(lds[cc + 2*j + 1][hw]) << 16);
        w1[j] = (unsigned int)bf16bits(lds[cc + 8 + 2*j + 0][hw])
              | ((unsigned int)bf16bits(lds[cc + 8 + 2*j + 1][hw]) << 16);
    }
    *(uint4*)(dst)     = v0;
    *(uint4*)(dst + 8) = v1;
}

// ---------------- K2b: kpT[b][hw][o] bf16 = (Wk.k+bk)^T via MFMA --------------
// block = 4 waves; wave = (o-half, 16-hw tile): acc[8] -> 32 AGPR, ~4 waves/SIMD
__global__ __launch_bounds__(256) void k_kproj(const unsigned short* __restrict__ kT,
                                               const unsigned short* __restrict__ Wkbf,
                                               const float* __restrict__ bk,
                                               unsigned short* __restrict__ kpT) {
    int b = blockIdx.y;
    int hwblk = blockIdx.x * 32;
    int t = threadIdx.x;
    int w = t >> 6, lane = t & 63;
    int hwt = w & 1, oh = w >> 1;     // wave -> (hw tile, o half)
    int n15 = lane & 15;
    int kg = lane >> 4;
    int hw = hwblk + hwt * 16 + n15;

    f32x4_t acc[8];
#pragma unroll
    for (int m = 0; m < 8; ++m) acc[m] = f32x4_t{0.f, 0.f, 0.f, 0.f};

    const unsigned short* kTrow = kT + ((size_t)b * HWN + hw) * 256 + kg * 8;
    const unsigned short* wbase = Wkbf + ((size_t)(oh * 128 + n15)) * 256 + kg * 8;

#pragma unroll 2
    for (int ks = 0; ks < 8; ++ks) {
        bf16x8_t bfrag = *reinterpret_cast<const bf16x8_t*>(kTrow + ks * 32);
#pragma unroll
        for (int m = 0; m < 8; ++m) {
            bf16x8_t afrag = *reinterpret_cast<const bf16x8_t*>(wbase + (size_t)m * 16 * 256 + ks * 32);
            acc[m] = __builtin_amdgcn_mfma_f32_16x16x32_bf16(afrag, bfrag, acc[m], 0, 0, 0);
        }
    }

    // epilogue: bias + bf16 -> LDS tile [32 hw][256 o] -> coalesced kpT write
    __shared__ unsigned short tile2[32 * 264];
    int hw_l = hwt * 16 + n15;
#pragma unroll
    for (int m = 0; m < 8; ++m) {
        ushort4 pk;
        unsigned short* pkp = (unsigned short*)&pk;
#pragma unroll
        for (int r = 0; r < 4; ++r) {
            int o = oh * 128 + m * 16 + kg * 4 + r;
            pkp[r] = bf16bits(acc[m][r] + bk[o]);
        }
        *(ushort4*)&tile2[hw_l * 264 + oh * 128 + m * 16 + kg * 4] = pk;
    }
    __syncthreads();
    int row = t >> 3, sub = t & 7;
    unsigned short* dst = kpT + ((size_t)b * HWN + hwblk + row) * 256 + sub * 32;
    const unsigned short* srcl = &tile2[row * 264 + sub * 32];
#pragma unroll
    for (int j = 0; j < 4; ++j)
        *(uint4*)(dst + j * 8) = *(const uint4*)(srcl + j * 8);
}

// ---------------- K3: sum-pass — A-frags hoisted per head, stream kpT ---------
// grid (64 hw strips of 64, 16 b); 4 waves; wave = one 16-hw tile
__global__ __launch_bounds__(256) void k_sums(const unsigned short* __restrict__ qphi,
                                              const unsigned short* __restrict__ qplo,
                                              const unsigned short* __restrict__ kpT,
                                              const int* __restrict__ mask,
                                              float* __restrict__ partial) {
    int b = blockIdx.y;
    int hwblk = blockIdx.x * 64;
    int t = threadIdx.x, w = t >> 6, lane = t & 63;
    int n15 = lane & 15, kg = lane >> 4;
    int hw = hwblk + w * 16 + n15;
    float mm = mask[b * HWN + hw] ? 0.0f : 1.0f;
    const unsigned short* brow  = kpT  + ((size_t)(b * HWN + hw)) * 256 + kg * 8;
    const unsigned short* ahi_b = qphi + ((size_t)(b * QPAD + n15)) * 256 + kg * 8;
    const unsigned short* alo_b = qplo + ((size_t)(b * QPAD + n15)) * 256 + kg * 8;
    float sums[7][4] = {};
#pragma unroll 1
    for (int n = 0; n < NH; ++n) {
        // hoist all A-frags for this head into registers (56 VGPR)
        bf16x8_t ahi[7], alo[7];
#pragma unroll
        for (int mt = 0; mt < 7; ++mt) {
            ahi[mt] = *reinterpret_cast<const bf16x8_t*>(ahi_b + (size_t)(mt * 16) * 256 + n * 32);
            alo[mt] = *reinterpret_cast<const bf16x8_t*>(alo_b + (size_t)(mt * 16) * 256 + n * 32);
        }
        bf16x8_t bfr = *reinterpret_cast<const bf16x8_t*>(brow + n * 32);
#pragma unroll
        for (int mt = 0; mt < 7; ++mt) {
            f32x4_t a2 = {0.f, 0.f, 0.f, 0.f};
            a2 = __builtin_amdgcn_mfma_f32_16x16x32_bf16(ahi[mt], bfr, a2, 0, 0, 0);
            a2 = __builtin_amdgcn_mfma_f32_16x16x32_bf16(alo[mt], bfr, a2, 0, 0, 0);
#pragma unroll
            for (int r = 0; r < 4; ++r)
                sums[mt][r] += __expf(a2[r]) * mm;
        }
    }
#pragma unroll
    for (int mt = 0; mt < 7; ++mt)
#pragma unroll
        for (int r = 0; r < 4; ++r) {
            float v = sums[mt][r];
            v += __shfl_xor(v, 1, 64);
            v += __shfl_xor(v, 2, 64);
            v += __shfl_xor(v, 4, 64);
            v += __shfl_xor(v, 8, 64);
            if (n15 == 0) {
                int qrow = mt * 16 + kg * 4 + r;
                partial[((size_t)b * QPAD + qrow) * 256 + blockIdx.x * 4 + w] = v;
            }
        }
}

// ---------------- K4: inv_sum[b,q] — one block per (b,q), 256-slot reduce -----
__global__ __launch_bounds__(256) void k_invsum(const float* __restrict__ partial,
                                                float* __restrict__ inv) {
    int blk = blockIdx.x;            // 0..1599
    int b = blk / QQ, qq = blk % QQ;
    const float* p = partial + ((size_t)b * QPAD + qq) * 256;
    int t = threadIdx.x;
    float v = p[t];
#pragma unroll
    for (int off = 32; off; off >>= 1) v += __shfl_xor(v, off, 64);
    __shared__ float red[4];
    if ((t & 63) == 0) red[t >> 6] = v;
    __syncthreads();
    if (t == 0) inv[blk] = 1.0f / (red[0] + red[1] + red[2] + red[3]);
}

// ---------------- K5: write-pass via MFMA — normalized output -----------------
// grid (16 hw strips of 256, 7 q tiles of 16, 16 b); wave owns 64 hw
// NOTE: LDS staging tile is PER-WAVE -> no __syncthreads needed anywhere.
__global__ __launch_bounds__(256) void k_write(const unsigned short* __restrict__ qphi,
                                               const unsigned short* __restrict__ qplo,
                                               const unsigned short* __restrict__ kpT,
                                               const int* __restrict__ mask,
                                               const float* __restrict__ inv,
                                               float* __restrict__ out) {
    int hws = blockIdx.x, qt = blockIdx.y, b = blockIdx.z;
    int t = threadIdx.x, w = t >> 6, lane = t & 63;
    int n15 = lane & 15, kg = lane >> 4;
    int hw0 = hws * 256 + w * 64;
    float mm[4];
#pragma unroll
    for (int ht = 0; ht < 4; ++ht)
        mm[ht] = mask[b * HWN + hw0 + ht * 16 + n15] ? 0.0f : 1.0f;
    float invq[4];
#pragma unroll
    for (int r = 0; r < 4; ++r) {
        int qrow = qt * 16 + kg * 4 + r;
        invq[r] = (qrow < QQ) ? inv[b * QQ + qrow] : 0.0f;
    }
    const unsigned short* ahi_b = qphi + ((size_t)(b * QPAD + qt * 16 + n15)) * 256 + kg * 8;
    const unsigned short* alo_b = qplo + ((size_t)(b * QPAD + qt * 16 + n15)) * 256 + kg * 8;
    const unsigned short* brow  = kpT  + ((size_t)(b * HWN + hw0 + n15)) * 256 + kg * 8;
    __shared__ float lt[4][16][68];   // per-wave 16q x 64hw staging (68: 16B-aligned rows)
#pragma unroll 1
    for (int n = 0; n < NH; ++n) {
        bf16x8_t bf[4];
#pragma unroll
        for (int ht = 0; ht < 4; ++ht)
            bf[ht] = *reinterpret_cast<const bf16x8_t*>(brow + (size_t)(ht * 16) * 256 + n * 32);
        bf16x8_t ahi = *reinterpret_cast<const bf16x8_t*>(ahi_b + n * 32);
        bf16x8_t alo = *reinterpret_cast<const bf16x8_t*>(alo_b + n * 32);
#pragma unroll
        for (int ht = 0; ht < 4; ++ht) {
            f32x4_t acc = {0.f, 0.f, 0.f, 0.f};
            acc = __builtin_amdgcn_mfma_f32_16x16x32_bf16(ahi, bf[ht], acc, 0, 0, 0);
            acc = __builtin_amdgcn_mfma_f32_16x16x32_bf16(alo, bf[ht], acc, 0, 0, 0);
#pragma unroll
            for (int r = 0; r < 4; ++r)
                lt[w][kg * 4 + r][ht * 16 + n15] = __expf(acc[r]) * mm[ht] * invq[r];
        }
        // same-wave LDS RAW: compiler inserts lgkmcnt wait; no barrier needed
#pragma unroll
        for (int j = 0; j < 4; ++j) {
            int rr = j * 4 + kg;
            int qrow = qt * 16 + rr;
            f32x4_t v4 = *(const f32x4_t*)&lt[w][rr][n15 * 4];
            if (qrow < QQ)
                __builtin_nontemporal_store(v4,
                    (f32x4_t*)(out + (((size_t)(b * QQ + qrow)) * NH + n) * HWN + hw0 + n15 * 4));
        }
    }
}

extern "C" void kernel_launch(void* const* d_in, const int* in_sizes, int n_in,
                              void* d_out, int out_size, void* d_ws, size_t ws_size,
                              hipStream_t stream) {
    const float* q    = (const float*)d_in[0];
    const float* k    = (const float*)d_in[1];
    const float* Wq   = (const float*)d_in[2];
    const float* bq   = (const float*)d_in[3];
    const float* Wk   = (const float*)d_in[4];
    const float* bk   = (const float*)d_in[5];
    const int*   mask = (const int*)d_in[6];
    float* out = (float*)d_out;

    char* base = (char*)d_ws;
    unsigned short* kT   = (unsigned short*)(base);              // 33,554,432 B
    unsigned short* kpT  = (unsigned short*)(base + 33554432);   // 33,554,432 B
    unsigned short* qphi = (unsigned short*)(base + 67108864);   //    917,504 B
    unsigned short* qplo = (unsigned short*)(base + 68026368);   //    917,504 B
    float*  WqT     = (float*)(base + 68943872);                 //    262,144 B
    unsigned short* Wkbf = (unsigned short*)(base + 69206016);   //    131,072 B
    float*  partial = (float*)(base + 69337088);                 //  1,835,008 B
    float*  inv     = (float*)(base + 71172096);                 //      6,400 B
    if (ws_size < (size_t)71178496) return;

    k_prep  <<<dim3(512), dim3(256), 0, stream>>>(Wq, Wk, WqT, Wkbf);
    k_qproj <<<dim3(448), dim3(256), 0, stream>>>(q, WqT, bq, qphi, qplo);
    k_tconv <<<dim3(64, 4, 16), dim3(256), 0, stream>>>(k, kT);
    k_kproj <<<dim3(128, 16), dim3(256), 0, stream>>>(kT, Wkbf, bk, kpT);
    k_sums  <<<dim3(64, 16), dim3(256), 0, stream>>>(qphi, qplo, kpT, mask, partial);
    k_invsum<<<dim3(1600), dim3(256), 0, stream>>>(partial, inv);
    k_write <<<dim3(16, 7, 16), dim3(256), 0, stream>>>(qphi, qplo, kpT, mask, inv, out);
}